// Round 20
// baseline (640.528 us; speedup 1.0000x reference)
//
#include <hip/hip_runtime.h>
#include <hip/hip_bf16.h>
#include <math.h>

// B=16, L=4096, E=512, H=8, D=64, k_top=16.
// Round 20: gemm_qk 2-K-steps-per-barrier. The per-t __syncthreads (with its
// vmcnt/lgkmcnt drain) is the known structural stall of the 2-barrier family;
// halve it: double-width LDS planes hold 2 sub-steps, one barrier covers a
// 96-MFMA region. W-frags for sub-step B reload into the same registers after
// cluster A (no concurrent buffering -> stays in the <=128-reg tier).
// Everything else identical to R19 (640us, passing).

#define B_ 16
#define L_ 4096
#define E_ 512
#define NCAND 18
#define KTOP 16

typedef __attribute__((ext_vector_type(8))) short bf16x8;
typedef __attribute__((ext_vector_type(4))) float f32x4;

__device__ __forceinline__ float2 cmul(float2 a, float2 b) {
  return make_float2(a.x*b.x - a.y*b.y, a.x*b.y + a.y*b.x);
}
__device__ __forceinline__ float2 cadd(float2 a, float2 b){return make_float2(a.x+b.x, a.y+b.y);}
__device__ __forceinline__ float2 csub(float2 a, float2 b){return make_float2(a.x-b.x, a.y-b.y);}
__device__ __forceinline__ float2 cnegi(float2 a){return make_float2(a.y, -a.x);}  // -i*a
__device__ __forceinline__ unsigned short bf16_rne(float x) {
  unsigned int u = __float_as_uint(x);
  unsigned int r = u + 0x7FFFu + ((u >> 16) & 1u);
  return (unsigned short)(r >> 16);
}
__device__ __forceinline__ float bf16_f(unsigned short h) {
  return __uint_as_float(((unsigned int)h) << 16);
}

// ---------------- register DFT helpers ----------------
__device__ __forceinline__ void dft4(float2 a, float2 b, float2 c, float2 d,
                                     float2& X0, float2& X1, float2& X2, float2& X3) {
  float2 t0 = cadd(a,c), t1 = csub(a,c), t2 = cadd(b,d), t3 = csub(b,d);
  X0 = cadd(t0, t2); X2 = csub(t0, t2);
  float2 it3 = cnegi(t3);
  X1 = cadd(t1, it3);
  X3 = csub(t1, it3);
}

__device__ __forceinline__ void dft16(float2* v) {
  float2 B[4][4];
#pragma unroll
  for (int p = 0; p < 4; ++p)
    dft4(v[p], v[p+4], v[p+8], v[p+12], B[p][0], B[p][1], B[p][2], B[p][3]);
  const float C1 = 0.92387953251128674f, S1 = 0.38268343236508978f;
  const float C2 = 0.70710678118654752f;
  B[1][1] = cmul(B[1][1], make_float2( C1, -S1));
  B[1][2] = cmul(B[1][2], make_float2( C2, -C2));
  B[1][3] = cmul(B[1][3], make_float2( S1, -C1));
  B[2][1] = cmul(B[2][1], make_float2( C2, -C2));
  B[2][2] = cnegi(B[2][2]);
  B[2][3] = cmul(B[2][3], make_float2(-C2, -C2));
  B[3][1] = cmul(B[3][1], make_float2( S1, -C1));
  B[3][2] = cmul(B[3][2], make_float2(-C2, -C2));
  B[3][3] = cmul(B[3][3], make_float2(-C1,  S1));
#pragma unroll
  for (int r = 0; r < 4; ++r)
    dft4(B[0][r], B[1][r], B[2][r], B[3][r], v[r], v[r+4], v[r+8], v[r+12]);
}

__device__ __forceinline__ void fft4096_stages(float2* buf, int tid,
                                               const float2* __restrict__ tw) {
  float2 z[16];
#pragma unroll
  for (int q = 0; q < 16; ++q) z[q] = buf[tid + 256*q];
  __syncthreads();
  dft16(z);
  {
    const int p = tid, pa = tid & 15;
    buf[p*16 + (0 ^ pa)] = z[0];
#pragma unroll
    for (int r = 1; r < 16; ++r)
      buf[p*16 + (r ^ pa)] = cmul(z[r], tw[p*r]);
  }
  __syncthreads();
  {
    const int a = tid >> 4, r = tid & 15;
    float2 v[16];
#pragma unroll
    for (int bb = 0; bb < 16; ++bb) v[bb] = buf[(a + 16*bb)*16 + (r ^ a)];
    __syncthreads();
    dft16(v);
    buf[a*256 + 0*16 + r] = v[0];
#pragma unroll
    for (int c = 1; c < 16; ++c)
      buf[a*256 + c*16 + r] = cmul(v[c], tw[16*a*c]);
  }
  __syncthreads();
  {
    float2 y[16];
#pragma unroll
    for (int a = 0; a < 16; ++a) y[a] = buf[256*a + tid];
    __syncthreads();
    dft16(y);
#pragma unroll
    for (int d = 0; d < 16; ++d) buf[tid + 256*d] = y[d];
  }
  __syncthreads();
}

// ---------------- conv_tile: fp32 (ntiles*128, 512) -> tiled bf16 [tile][t][lk][128][8] ----------------
template<bool SPLIT>
__global__ __launch_bounds__(256) void conv_tile(
    const float* __restrict__ Xsrc,
    unsigned short* __restrict__ Thi, unsigned short* __restrict__ Tlo)
{
  const int bx = blockIdx.x;
  const int t  = blockIdx.y;
  const int tid = threadIdx.x;
  const int r = tid >> 1;
  const int h = tid & 1;
  const float* src = Xsrc + ((size_t)(bx*128 + r))*512 + t*32 + h*16;
  float xa[16];
#pragma unroll
  for (int q = 0; q < 4; ++q) {
    float4 v = *reinterpret_cast<const float4*>(src + 4*q);
    xa[4*q+0]=v.x; xa[4*q+1]=v.y; xa[4*q+2]=v.z; xa[4*q+3]=v.w;
  }
  size_t base = ((size_t)(bx*16 + t))*4096;
#pragma unroll
  for (int c = 0; c < 2; ++c) {
    int lk = h*2 + c;
    bf16x8 vh, vl;
#pragma unroll
    for (int e = 0; e < 8; ++e) {
      unsigned short hh = bf16_rne(xa[c*8+e]);
      vh[e] = (short)hh;
      if (SPLIT) vl[e] = (short)bf16_rne(xa[c*8+e] - bf16_f(hh));
    }
    *reinterpret_cast<bf16x8*>(Thi + base + ((size_t)lk*128 + r)*8) = vh;
    if (SPLIT)
      *reinterpret_cast<bf16x8*>(Tlo + base + ((size_t)lk*128 + r)*8) = vl;
  }
}

// ---------------- gemm_qk: merged Q+K, split-bf16, 2 K-steps per barrier ----------------
// grid (2, 1024, 2): x=ny (n-half), y=lt (64-l tile), z=sel (Q/K).
// 256 threads = 4 waves, wave w: n in [ny*256 + w*64, +64), l full 64. acc=64 AGPR.
// LDS planes hold 2 sub-steps (8KB/plane hi + 8KB lo); 8 barriers per block.
__global__ __launch_bounds__(256, 4) void gemm_qk(
    const float* __restrict__ Xq, const float* __restrict__ Xk,
    const unsigned short* __restrict__ Wqhi, const unsigned short* __restrict__ Wqlo,
    const unsigned short* __restrict__ Wkhi, const unsigned short* __restrict__ Wklo,
    const float* __restrict__ bq, const float* __restrict__ bk,
    float* __restrict__ Yq, float* __restrict__ Yk)
{
  __shared__ unsigned short Xh[2][4096], Xl[2][4096];   // [pair-plane][2 substeps x 2048]
  const int sel = blockIdx.z;
  const float* X = sel ? Xk : Xq;
  const unsigned short* Whi = sel ? Wkhi : Wqhi;
  const unsigned short* Wlo = sel ? Wklo : Wqlo;
  const float* bias = sel ? bk : bq;
  float* Y = sel ? Yk : Yq;

  const int tid  = threadIdx.x;
  const int ny   = blockIdx.x;
  const int lt   = blockIdx.y;
  const int wave = tid >> 6;
  const int lane = tid & 63;
  const int lr   = lane & 15;
  const int lk   = lane >> 4;
  const int n0   = ny*256 + wave*64;
  const int cr   = tid >> 2;
  const int ch   = tid & 3;
  const int t0   = ((lt << 1) | ny) & 15;

  f32x4 acc[4][4];
#pragma unroll
  for (int i = 0; i < 4; ++i)
#pragma unroll
    for (int j = 0; j < 4; ++j) acc[i][j] = (f32x4){0.f,0.f,0.f,0.f};

  const float* Xb = X + ((size_t)(lt*64 + cr))*512 + ch*8;
  const int cu = ((ch*64 + cr) ^ (ch*2))*8;   // short offset within a sub-step

  for (int itp = 0; itp < 8; ++itp) {
    const int ta = (t0 + 2*itp) & 15;
    const int tb = (t0 + 2*itp + 1) & 15;
    const int p  = itp & 1;
    // convert both sub-steps into plane p (sub-step A at +0, B at +2048 shorts)
#pragma unroll
    for (int s = 0; s < 2; ++s) {
      const int ts = s ? tb : ta;
      float4 v0 = *reinterpret_cast<const float4*>(Xb + ts*32);
      float4 v1 = *reinterpret_cast<const float4*>(Xb + ts*32 + 4);
      float xa[8] = {v0.x,v0.y,v0.z,v0.w,v1.x,v1.y,v1.z,v1.w};
      bf16x8 vh, vl;
#pragma unroll
      for (int e = 0; e < 8; ++e) {
        unsigned short hh = bf16_rne(xa[e]);
        vh[e] = (short)hh;
        vl[e] = (short)bf16_rne(xa[e] - bf16_f(hh));
      }
      *reinterpret_cast<bf16x8*>(&Xh[p][s*2048 + cu]) = vh;
      *reinterpret_cast<bf16x8*>(&Xl[p][s*2048 + cu]) = vl;
    }
    // W frags for sub-step A issued before the barrier (latency under barrier)
    bf16x8 ah[4], al[4];
#pragma unroll
    for (int i = 0; i < 4; ++i) {
      int n = n0 + i*16 + lr;
      size_t o = ((size_t)((n>>7)*16 + ta))*4096 + ((size_t)lk*128 + (n&127))*8;
      ah[i] = *reinterpret_cast<const bf16x8*>(Whi + o);
      al[i] = *reinterpret_cast<const bf16x8*>(Wlo + o);
    }
    __syncthreads();

    // ---- cluster A ----
    __builtin_amdgcn_s_setprio(1);
#pragma unroll
    for (int j = 0; j < 4; ++j) {
      int u = ((lk*64 + (j*16 + lr)) ^ (lk*2))*8;
      bf16x8 bh = *reinterpret_cast<const bf16x8*>(&Xh[p][u]);
      bf16x8 bl = *reinterpret_cast<const bf16x8*>(&Xl[p][u]);
#pragma unroll
      for (int i = 0; i < 4; ++i)
        acc[i][j] = __builtin_amdgcn_mfma_f32_16x16x32_bf16(ah[i], bh, acc[i][j], 0, 0, 0);
#pragma unroll
      for (int i = 0; i < 4; ++i)
        acc[i][j] = __builtin_amdgcn_mfma_f32_16x16x32_bf16(ah[i], bl, acc[i][j], 0, 0, 0);
#pragma unroll
      for (int i = 0; i < 4; ++i)
        acc[i][j] = __builtin_amdgcn_mfma_f32_16x16x32_bf16(al[i], bh, acc[i][j], 0, 0, 0);
    }
    __builtin_amdgcn_s_setprio(0);

    // W frags for sub-step B (reuse registers; latency covered by other waves)
#pragma unroll
    for (int i = 0; i < 4; ++i) {
      int n = n0 + i*16 + lr;
      size_t o = ((size_t)((n>>7)*16 + tb))*4096 + ((size_t)lk*128 + (n&127))*8;
      ah[i] = *reinterpret_cast<const bf16x8*>(Whi + o);
      al[i] = *reinterpret_cast<const bf16x8*>(Wlo + o);
    }

    // ---- cluster B ----
    __builtin_amdgcn_s_setprio(1);
#pragma unroll
    for (int j = 0; j < 4; ++j) {
      int u = ((lk*64 + (j*16 + lr)) ^ (lk*2))*8 + 2048;
      bf16x8 bh = *reinterpret_cast<const bf16x8*>(&Xh[p][u]);
      bf16x8 bl = *reinterpret_cast<const bf16x8*>(&Xl[p][u]);
#pragma unroll
      for (int i = 0; i < 4; ++i)
        acc[i][j] = __builtin_amdgcn_mfma_f32_16x16x32_bf16(ah[i], bh, acc[i][j], 0, 0, 0);
#pragma unroll
      for (int i = 0; i < 4; ++i)
        acc[i][j] = __builtin_amdgcn_mfma_f32_16x16x32_bf16(ah[i], bl, acc[i][j], 0, 0, 0);
#pragma unroll
      for (int i = 0; i < 4; ++i)
        acc[i][j] = __builtin_amdgcn_mfma_f32_16x16x32_bf16(al[i], bh, acc[i][j], 0, 0, 0);
    }
    __builtin_amdgcn_s_setprio(0);
  }

  const int bb = lt >> 6;
  const int lbase = (lt & 63)*64;
#pragma unroll
  for (int i = 0; i < 4; ++i) {
    int n = n0 + i*16 + lk*4;
#pragma unroll
    for (int j = 0; j < 4; ++j) {
      int l = lbase + j*16 + lr;
#pragma unroll
      for (int r = 0; r < 4; ++r) {
        Y[((size_t)(bb*512 + n + r))*4096 + l] = acc[i][j][r] + bias[n + r];
      }
    }
  }
}

// ---------------- gemm_ov: fused values conversion, pure bf16, bf16 output ----------------
__global__ __launch_bounds__(512) void gemm_ov(
    const float* __restrict__ V, const unsigned short* __restrict__ Wct,
    const float* __restrict__ bias, unsigned short* __restrict__ Y16)
{
  __shared__ unsigned short Vs[2][256*8];
  const int tid  = threadIdx.x;
  const int bx   = blockIdx.x;
  const int wave = tid >> 6;
  const int lane = tid & 63;
  const int lr   = lane & 15;
  const int lk   = lane >> 4;
  const int n0   = wave*64;
  const int cr   = tid >> 3;
  const int ch   = tid & 7;
  const int clk  = ch >> 1;
  const int chh  = ch & 1;
  const int coff = (((clk*64 + cr) ^ clk)*8 + chh*4);
  const int t0   = bx & 15;

  f32x4 acc[4][4];
#pragma unroll
  for (int i = 0; i < 4; ++i)
#pragma unroll
    for (int j = 0; j < 4; ++j) acc[i][j] = (f32x4){0.f,0.f,0.f,0.f};

  const float* Vb = V + (size_t)bx*64*512 + (size_t)cr*512 + ch*4;
  float4 xv = *reinterpret_cast<const float4*>(Vb + t0*32);

  for (int it = 0; it < 16; ++it) {
    const int t = (t0 + it) & 15;
    const int p = it & 1;
    uint2 hi2 = make_uint2(
        (unsigned)bf16_rne(xv.x) | ((unsigned)bf16_rne(xv.y) << 16),
        (unsigned)bf16_rne(xv.z) | ((unsigned)bf16_rne(xv.w) << 16));
    *reinterpret_cast<uint2*>(&Vs[p][coff]) = hi2;
    float4 xnext;
    if (it < 15) {
      int tn = (t0 + it + 1) & 15;
      xnext = *reinterpret_cast<const float4*>(Vb + tn*32);
    }
    __syncthreads();

    bf16x8 av[4];
#pragma unroll
    for (int i = 0; i < 4; ++i) {
      int u = ((lk*64 + i*16 + lr) ^ lk)*8;
      av[i] = *reinterpret_cast<const bf16x8*>(&Vs[p][u]);
    }
#pragma unroll
    for (int j = 0; j < 4; ++j) {
      int n = n0 + j*16 + lr;
      size_t o = ((size_t)((n>>7)*16 + t))*4096 + ((size_t)lk*128 + (n&127))*8;
      bf16x8 bw = *reinterpret_cast<const bf16x8*>(Wct + o);
#pragma unroll
      for (int i = 0; i < 4; ++i)
        acc[i][j] = __builtin_amdgcn_mfma_f32_16x16x32_bf16(av[i], bw, acc[i][j], 0, 0, 0);
    }
    if (it < 15) xv = xnext;
  }

#pragma unroll
  for (int i = 0; i < 4; ++i) {
#pragma unroll
    for (int j = 0; j < 4; ++j) {
      int n = n0 + j*16 + lr;
      float bs = bias[n];
#pragma unroll
      for (int r = 0; r < 4; ++r) {
        int m = bx*64 + i*16 + lk*4 + r;
        Y16[(size_t)m*512 + n] = bf16_rne(acc[i][j][r] + bs);
      }
    }
  }
}

// ---------------- combine: Wc = Wo@Wv, bc = Wo@bv + bo ----------------
__global__ __launch_bounds__(256) void combine_kernel(
    const float* __restrict__ Wo, const float* __restrict__ Wv,
    const float* __restrict__ bv, const float* __restrict__ bo,
    float* __restrict__ Wc, float* __restrict__ bc)
{
  int n = blockIdx.x;
  int tid = threadIdx.x;
  float a0 = 0.f, a1 = 0.f;
  for (int j = 0; j < 512; ++j) {
    float wo = Wo[(size_t)n*512 + j];
    a0 += wo * Wv[(size_t)j*512 + tid];
    a1 += wo * Wv[(size_t)j*512 + tid + 256];
  }
  Wc[(size_t)n*512 + tid]       = a0;
  Wc[(size_t)n*512 + tid + 256] = a1;

  float p = 0.f;
  for (int j = tid; j < 512; j += 256) p += Wo[(size_t)n*512 + j] * bv[j];
  __shared__ float red[256];
  red[tid] = p; __syncthreads();
  for (int off = 128; off > 0; off >>= 1) {
    if (tid < off) red[tid] += red[tid + off];
    __syncthreads();
  }
  if (tid == 0) bc[n] = red[0] + bo[n];
}

// ---------------- twiddles ----------------
__global__ void init_tw_kernel(float2* __restrict__ tw) {
  int k = blockIdx.x * 256 + threadIdx.x;
  if (k < 4096) {
    double ang = -2.0 * M_PI * (double)k / 4096.0;
    tw[k] = make_float2((float)cos(ang), (float)sin(ang));
  }
}

// ---------------- packed FFT -> half-spectrum partials (Hermitian) ----------------
template<int CHB>
__global__ __launch_bounds__(256) void fft_corr_kernel(
    const float* __restrict__ Qt, const float* __restrict__ Kt,
    const float2* __restrict__ tw, float2* __restrict__ Spart)
{
  __shared__ float2 buf[4096];
  const int NG = 512 / CHB;
  const int b = blockIdx.x / NG;
  const int g = blockIdx.x % NG;
  const int tid = threadIdx.x;

  float2 acc[8];
#pragma unroll
  for (int m = 0; m < 8; ++m) acc[m] = make_float2(0.f, 0.f);

  for (int cc = 0; cc < CHB; ++cc) {
    const float* Qr = Qt + ((size_t)b*512 + g*CHB + cc) * 4096;
    const float* Kr = Kt + ((size_t)b*512 + g*CHB + cc) * 4096;
#pragma unroll
    for (int j = 0; j < 4; ++j) {
      int l0 = 4*(tid + 256*j);
      float4 q4 = *reinterpret_cast<const float4*>(Qr + l0);
      float4 k4 = *reinterpret_cast<const float4*>(Kr + l0);
      buf[l0+0] = make_float2(q4.x, k4.x);
      buf[l0+1] = make_float2(q4.y, k4.y);
      buf[l0+2] = make_float2(q4.z, k4.z);
      buf[l0+3] = make_float2(q4.w, k4.w);
    }
    __syncthreads();

    fft4096_stages(buf, tid, tw);

#pragma unroll
    for (int m = 0; m < 8; ++m) {
      int f = tid + 256*m;
      float2 zf = buf[f];
      float2 zm = buf[(4096 - f) & 4095];
      float2 qf = make_float2(0.5f*(zf.x + zm.x), 0.5f*(zf.y - zm.y));
      float2 df = make_float2(0.5f*(zf.x - zm.x), 0.5f*(zf.y + zm.y));
      float2 kf = make_float2(df.y, -df.x);
      acc[m].x += qf.x*kf.x + qf.y*kf.y;
      acc[m].y += qf.y*kf.x - qf.x*kf.y;   // == 0 at f==0
    }
    if (tid == 0) {
      float2 z2 = buf[2048];
      acc[0].y += z2.x * z2.y;
    }
    __syncthreads();
  }
  float2* Sp = Spart + ((size_t)(b*NG + g)) * 2048;
#pragma unroll
  for (int m = 0; m < 8; ++m) Sp[tid + 256*m] = acc[m];
}

// ---------------- reduce half-spectrum over groups, store conj (except bin0 pack) ----------------
__global__ __launch_bounds__(256) void reduce_spart_kernel(
    const float2* __restrict__ Spart, float2* __restrict__ S, int ng)
{
  const int b  = blockIdx.x >> 3;
  const int f  = ((blockIdx.x & 7) << 8) | threadIdx.x;
  float sx = 0.f, sy = 0.f;
  const float2* base = Spart + (size_t)b * ng * 2048 + f;
  for (int g = 0; g < ng; ++g) {
    float2 v = base[(size_t)g * 2048];
    sx += v.x; sy += v.y;
  }
  S[(size_t)b*2048 + f] = (f == 0) ? make_float2(sx, sy) : make_float2(sx, -sy);
}

// ---------------- inverse FFT per batch (Hermitian reconstruct) -> corr_mean ----------------
__global__ __launch_bounds__(256) void ifft_kernel(
    const float2* __restrict__ S, const float2* __restrict__ tw,
    float* __restrict__ corr)
{
  __shared__ float2 buf[4096];
  const int b = blockIdx.x;
  const int tid = threadIdx.x;
#pragma unroll
  for (int m = 0; m < 8; ++m) {
    int f = tid + 256*m;
    float2 s = S[(size_t)b*2048 + f];
    if (f == 0) {
      buf[0]    = make_float2(s.x, 0.f);
      buf[2048] = make_float2(s.y, 0.f);
    } else {
      buf[f]        = s;
      buf[4096 - f] = make_float2(s.x, -s.y);
    }
  }
  __syncthreads();
  fft4096_stages(buf, tid, tw);
  const float scale = 1.0f / (512.0f * 4096.0f);
#pragma unroll
  for (int m = 0; m < 16; ++m) {
    int t = tid + 256*m;
    corr[(size_t)b*4096 + t] = buf[t].x * scale;
  }
}

// ---------------- top-18 per batch + ambiguity flag ----------------
__global__ __launch_bounds__(256) void topk_kernel(
    const float* __restrict__ corr, float* __restrict__ cand_val,
    int* __restrict__ cand_idx, int* __restrict__ flags)
{
  __shared__ float vals[4096];
  __shared__ float rv[256];
  __shared__ int   ri[256];
  const int b = blockIdx.x;
  const int tid = threadIdx.x;
#pragma unroll
  for (int r = 0; r < 16; ++r) vals[tid + 256*r] = corr[(size_t)b*4096 + tid + 256*r];
  __syncthreads();

  for (int it = 0; it < NCAND; ++it) {
    float best = -1e30f; int bi = -1;
#pragma unroll
    for (int r = 0; r < 16; ++r) {
      int i = tid + 256*r;
      float v = vals[i];
      if (v > best) { best = v; bi = i; }
    }
    rv[tid] = best; ri[tid] = bi;
    __syncthreads();
    for (int off = 128; off > 0; off >>= 1) {
      if (tid < off) {
        float v2 = rv[tid + off]; int i2 = ri[tid + off];
        if (v2 > rv[tid] || (v2 == rv[tid] && i2 < ri[tid])) { rv[tid] = v2; ri[tid] = i2; }
      }
      __syncthreads();
    }
    if (tid == 0) {
      cand_val[b*NCAND + it] = rv[0];
      cand_idx[b*NCAND + it] = ri[0];
      vals[ri[0]] = -1e30f;
    }
    __syncthreads();
  }
  if (tid == 0)
    flags[b] = (cand_val[b*NCAND + 15] - cand_val[b*NCAND + 16] < 2e-6f) ? 1 : 0;
}

// ---------------- exact refinement: read-once, all 18 taus ----------------
__global__ __launch_bounds__(256) void refine_kernel(
    const float* __restrict__ Qt, const float* __restrict__ Kt,
    const int* __restrict__ cand_idx, const int* __restrict__ flags,
    float* __restrict__ refpart)
{
  const int b = blockIdx.x >> 5;
  const int chunk = blockIdx.x & 31;
  if (!flags[b]) return;
  __shared__ float Qs[4096];
  __shared__ float red[4*NCAND];
  const int tid = threadIdx.x;
  int taus[NCAND];
#pragma unroll
  for (int i = 0; i < NCAND; ++i) taus[i] = cand_idx[b*NCAND + i];
  float acc[NCAND];
#pragma unroll
  for (int i = 0; i < NCAND; ++i) acc[i] = 0.f;

  for (int cc = 0; cc < 16; ++cc) {
    int c = chunk*16 + cc;
    const float* Qc = Qt + ((size_t)b*512 + c)*4096;
    const float* Kc = Kt + ((size_t)b*512 + c)*4096;
    __syncthreads();
#pragma unroll
    for (int rr = 0; rr < 4; ++rr) {
      int l4 = (tid + 256*rr)*4;
      *reinterpret_cast<float4*>(&Qs[l4]) = *reinterpret_cast<const float4*>(Qc + l4);
    }
    __syncthreads();
#pragma unroll 2
    for (int j = 0; j < 16; ++j) {
      int l = tid + 256*j;
      float kv = Kc[l];
#pragma unroll
      for (int i = 0; i < NCAND; ++i)
        acc[i] += Qs[(l + taus[i]) & 4095] * kv;
    }
  }
#pragma unroll
  for (int i = 0; i < NCAND; ++i) {
    float v = acc[i];
    for (int off = 32; off > 0; off >>= 1) v += __shfl_down(v, off);
    if ((tid & 63) == 0) red[(tid >> 6)*NCAND + i] = v;
  }
  __syncthreads();
  if (tid < NCAND) {
    float s = red[tid] + red[NCAND + tid] + red[2*NCAND + tid] + red[3*NCAND + tid];
    refpart[(size_t)(b*32 + chunk)*NCAND + tid] = s;
  }
}

// ---------------- select top-16 of 18 (with inline refinement sum), softmax ----------------
__global__ void probs_kernel(const float* __restrict__ cand_val,
                             const float* __restrict__ refpart,
                             const int* __restrict__ flags,
                             const int* __restrict__ cand_idx,
                             float* __restrict__ probs, int* __restrict__ delays)
{
  int b = blockIdx.x;
  __shared__ float vloc[NCAND];
  int t = threadIdx.x;
  if (t < NCAND) {
    float v = cand_val[b*NCAND + t];
    if (flags[b]) {
      double s = 0.0;
      for (int g = 0; g < 32; ++g) s += (double)refpart[(size_t)(b*32 + g)*NCAND + t];
      v = (float)(s / 512.0);
    }
    vloc[t] = v;
  }
  __syncthreads();
  if (t != 0) return;
  float v[NCAND]; int ix[NCAND]; bool used[NCAND];
  for (int i = 0; i < NCAND; ++i) {
    v[i] = vloc[i]; ix[i] = cand_idx[b*NCAND + i]; used[i] = false;
  }
  float sel_v[KTOP]; int sel_i[KTOP];
  for (int k = 0; k < KTOP; ++k) {
    int best = -1;
    for (int i = 0; i < NCAND; ++i) {
      if (used[i]) continue;
      if (best < 0 || v[i] > v[best] || (v[i] == v[best] && ix[i] < ix[best])) best = i;
    }
    used[best] = true; sel_v[k] = v[best]; sel_i[k] = ix[best];
  }
  float mx = sel_v[0];
  for (int k = 1; k < KTOP; ++k) mx = fmaxf(mx, sel_v[k]);
  float e[KTOP]; float se = 0.f;
  for (int k = 0; k < KTOP; ++k) { e[k] = __expf(sel_v[k] - mx); se += e[k]; }
  for (int k = 0; k < KTOP; ++k) {
    probs[b*KTOP + k]  = e[k] / se;
    delays[b*KTOP + k] = sel_i[k];
  }
}

// ---------------- shift-aggregate: bf16 OV gather, XCD-pinned batches ----------------
__global__ __launch_bounds__(256) void agg_kernel(
    const unsigned short* __restrict__ OV, const float* __restrict__ probs,
    const int* __restrict__ delays, float* __restrict__ out)
{
  int half = blockIdx.x >> 13;
  int bid2 = blockIdx.x & 8191;
  int b  = half*8 + (bid2 & 7);
  int l  = (bid2 >> 3) * 4 + (threadIdx.x >> 6);
  int c8 = (threadIdx.x & 63) << 3;
  float p[KTOP]; int d[KTOP];
#pragma unroll
  for (int i = 0; i < KTOP; ++i) { p[i] = probs[b*KTOP + i]; d[i] = delays[b*KTOP + i]; }
  float acc[8];
#pragma unroll
  for (int j = 0; j < 8; ++j) acc[j] = 0.f;
#pragma unroll
  for (int i = 0; i < KTOP; ++i) {
    int ls = (l + d[i]) & 4095;
    uint4 v = *reinterpret_cast<const uint4*>(OV + ((size_t)((b << 12) | ls))*512 + c8);
    unsigned int uu[4] = {v.x, v.y, v.z, v.w};
    float pi = p[i];
#pragma unroll
    for (int t = 0; t < 4; ++t) {
      acc[2*t]   += pi * __uint_as_float(uu[t] << 16);
      acc[2*t+1] += pi * __uint_as_float(uu[t] & 0xFFFF0000u);
    }
  }
  float* dst = out + ((size_t)((b << 12) | l))*512 + c8;
  *reinterpret_cast<float4*>(dst)     = make_float4(acc[0], acc[1], acc[2], acc[3]);
  *reinterpret_cast<float4*>(dst + 4) = make_float4(acc[4], acc[5], acc[6], acc[7]);
}

// ---------------- launch ----------------
extern "C" void kernel_launch(void* const* d_in, const int* in_sizes, int n_in,
                              void* d_out, int out_size, void* d_ws, size_t ws_size,
                              hipStream_t stream)
{
  const float* queries = (const float*)d_in[0];
  const float* keys    = (const float*)d_in[1];
  const float* values  = (const float*)d_in[2];
  const float* Wq = (const float*)d_in[3];
  const float* bq = (const float*)d_in[4];
  const float* Wk = (const float*)d_in[5];
  const float* bk = (const float*)d_in[6];
  const float* Wv = (const float*)d_in[7];
  const float* bv = (const float*)d_in[8];
  const float* Wo = (const float*)d_in[9];
  const float* bo = (const float*)d_in[10];

  const size_t WT = (size_t)E_*E_*2;
  const size_t fixed = (size_t)B_*E_*L_*4
                     + (size_t)B_*2048*8
                     + (size_t)B_*L_*4
                     + (size_t)E_*E_*4 + E_*4
                     + (size_t)4096*8
                     + (size_t)B_*NCAND*8 + B_*4
                     + (size_t)B_*KTOP*8
                     + (size_t)B_*32*NCAND*4
                     + 5*WT;
  int NG;
  if (ws_size >= fixed + (size_t)B_*128*2048*8)      NG = 128;
  else if (ws_size >= fixed + (size_t)B_*64*2048*8)  NG = 64;
  else                                               NG = 32;

  char* ws = (char*)d_ws;
  size_t off = 0;
  float* Qt   = (float*)(ws + off);    off += (size_t)B_*E_*L_*4;
  float2* Spart = (float2*)(ws + off); off += (size_t)B_*NG*2048*8;
  float2* S   = (float2*)(ws + off);   off += (size_t)B_*2048*8;
  float* corr = (float*)(ws + off);    off += (size_t)B_*L_*4;
  float* Wc   = (float*)(ws + off);    off += (size_t)E_*E_*4;
  float* bc   = (float*)(ws + off);    off += (size_t)E_*4;
  float2* tw  = (float2*)(ws + off);   off += (size_t)4096*8;
  float* cand_val = (float*)(ws + off); off += (size_t)B_*NCAND*4;
  int*   cand_idx = (int*)(ws + off);   off += (size_t)B_*NCAND*4;
  int*   flags    = (int*)(ws + off);   off += (size_t)B_*4;
  float* probs    = (float*)(ws + off); off += (size_t)B_*KTOP*4;
  int*   delays   = (int*)(ws + off);   off += (size_t)B_*KTOP*4;
  float* refpart  = (float*)(ws + off); off += (size_t)B_*32*NCAND*4;
  unsigned short* Wqhi = (unsigned short*)(ws + off); off += WT;
  unsigned short* Wqlo = (unsigned short*)(ws + off); off += WT;
  unsigned short* Wkhi = (unsigned short*)(ws + off); off += WT;
  unsigned short* Wklo = (unsigned short*)(ws + off); off += WT;
  unsigned short* Wcthi = (unsigned short*)(ws + off); off += WT;

  float* Kt = (float*)d_out;                  // d_out is K scratch until agg
  unsigned short* OV = (unsigned short*)Qt;   // bf16 OV overlays Qt after refine

  init_tw_kernel<<<16, 256, 0, stream>>>(tw);
  conv_tile<true><<<dim3(4,16), 256, 0, stream>>>(Wq, Wqhi, Wqlo);
  conv_tile<true><<<dim3(4,16), 256, 0, stream>>>(Wk, Wkhi, Wklo);
  combine_kernel<<<E_, 256, 0, stream>>>(Wo, Wv, bv, bo, Wc, bc);
  conv_tile<false><<<dim3(4,16), 256, 0, stream>>>(Wc, Wcthi, Wcthi);

  gemm_qk<<<dim3(2, 1024, 2), 256, 0, stream>>>(queries, keys, Wqhi, Wqlo, Wkhi, Wklo,
                                                bq, bk, Qt, Kt);

  if (NG == 128)
    fft_corr_kernel<4><<<B_*128, 256, 0, stream>>>(Qt, Kt, tw, Spart);
  else if (NG == 64)
    fft_corr_kernel<8><<<B_*64, 256, 0, stream>>>(Qt, Kt, tw, Spart);
  else
    fft_corr_kernel<16><<<B_*32, 256, 0, stream>>>(Qt, Kt, tw, Spart);
  reduce_spart_kernel<<<B_*8, 256, 0, stream>>>(Spart, S, NG);
  ifft_kernel<<<B_, 256, 0, stream>>>(S, tw, corr);
  topk_kernel<<<B_, 256, 0, stream>>>(corr, cand_val, cand_idx, flags);
  refine_kernel<<<B_*32, 256, 0, stream>>>(Qt, Kt, cand_idx, flags, refpart);
  probs_kernel<<<B_, 64, 0, stream>>>(cand_val, refpart, flags, cand_idx, probs, delays);

  gemm_ov<<<1024, 512, 0, stream>>>(values, Wcthi, bc, OV);
  agg_kernel<<<16384, 256, 0, stream>>>(OV, probs, delays, (float*)d_out);
}

// Round 21
// 635.008 us; speedup vs baseline: 1.0087x; 1.0087x over previous
//
#include <hip/hip_runtime.h>
#include <hip/hip_bf16.h>
#include <math.h>

// B=16, L=4096, E=512, H=8, D=64, k_top=16.
// Round 21: lock in best-measured configuration (R18, 636us). The 2-barrier
// gemm family is exhausted (6 variants, 240-253us); all other kernels at
// measured local ceilings. gemm_qk: 512-thr single-conversion (X read once);
// half-spectrum FFT; finalize merged into probs; single agg launch.

#define B_ 16
#define L_ 4096
#define E_ 512
#define NCAND 18
#define KTOP 16

typedef __attribute__((ext_vector_type(8))) short bf16x8;
typedef __attribute__((ext_vector_type(4))) float f32x4;

__device__ __forceinline__ float2 cmul(float2 a, float2 b) {
  return make_float2(a.x*b.x - a.y*b.y, a.x*b.y + a.y*b.x);
}
__device__ __forceinline__ float2 cadd(float2 a, float2 b){return make_float2(a.x+b.x, a.y+b.y);}
__device__ __forceinline__ float2 csub(float2 a, float2 b){return make_float2(a.x-b.x, a.y-b.y);}
__device__ __forceinline__ float2 cnegi(float2 a){return make_float2(a.y, -a.x);}  // -i*a
__device__ __forceinline__ unsigned short bf16_rne(float x) {
  unsigned int u = __float_as_uint(x);
  unsigned int r = u + 0x7FFFu + ((u >> 16) & 1u);
  return (unsigned short)(r >> 16);
}
__device__ __forceinline__ float bf16_f(unsigned short h) {
  return __uint_as_float(((unsigned int)h) << 16);
}

// ---------------- register DFT helpers ----------------
__device__ __forceinline__ void dft4(float2 a, float2 b, float2 c, float2 d,
                                     float2& X0, float2& X1, float2& X2, float2& X3) {
  float2 t0 = cadd(a,c), t1 = csub(a,c), t2 = cadd(b,d), t3 = csub(b,d);
  X0 = cadd(t0, t2); X2 = csub(t0, t2);
  float2 it3 = cnegi(t3);
  X1 = cadd(t1, it3);
  X3 = csub(t1, it3);
}

__device__ __forceinline__ void dft16(float2* v) {
  float2 B[4][4];
#pragma unroll
  for (int p = 0; p < 4; ++p)
    dft4(v[p], v[p+4], v[p+8], v[p+12], B[p][0], B[p][1], B[p][2], B[p][3]);
  const float C1 = 0.92387953251128674f, S1 = 0.38268343236508978f;
  const float C2 = 0.70710678118654752f;
  B[1][1] = cmul(B[1][1], make_float2( C1, -S1));
  B[1][2] = cmul(B[1][2], make_float2( C2, -C2));
  B[1][3] = cmul(B[1][3], make_float2( S1, -C1));
  B[2][1] = cmul(B[2][1], make_float2( C2, -C2));
  B[2][2] = cnegi(B[2][2]);
  B[2][3] = cmul(B[2][3], make_float2(-C2, -C2));
  B[3][1] = cmul(B[3][1], make_float2( S1, -C1));
  B[3][2] = cmul(B[3][2], make_float2(-C2, -C2));
  B[3][3] = cmul(B[3][3], make_float2(-C1,  S1));
#pragma unroll
  for (int r = 0; r < 4; ++r)
    dft4(B[0][r], B[1][r], B[2][r], B[3][r], v[r], v[r+4], v[r+8], v[r+12]);
}

__device__ __forceinline__ void fft4096_stages(float2* buf, int tid,
                                               const float2* __restrict__ tw) {
  float2 z[16];
#pragma unroll
  for (int q = 0; q < 16; ++q) z[q] = buf[tid + 256*q];
  __syncthreads();
  dft16(z);
  {
    const int p = tid, pa = tid & 15;
    buf[p*16 + (0 ^ pa)] = z[0];
#pragma unroll
    for (int r = 1; r < 16; ++r)
      buf[p*16 + (r ^ pa)] = cmul(z[r], tw[p*r]);
  }
  __syncthreads();
  {
    const int a = tid >> 4, r = tid & 15;
    float2 v[16];
#pragma unroll
    for (int bb = 0; bb < 16; ++bb) v[bb] = buf[(a + 16*bb)*16 + (r ^ a)];
    __syncthreads();
    dft16(v);
    buf[a*256 + 0*16 + r] = v[0];
#pragma unroll
    for (int c = 1; c < 16; ++c)
      buf[a*256 + c*16 + r] = cmul(v[c], tw[16*a*c]);
  }
  __syncthreads();
  {
    float2 y[16];
#pragma unroll
    for (int a = 0; a < 16; ++a) y[a] = buf[256*a + tid];
    __syncthreads();
    dft16(y);
#pragma unroll
    for (int d = 0; d < 16; ++d) buf[tid + 256*d] = y[d];
  }
  __syncthreads();
}

// ---------------- conv_tile: fp32 (ntiles*128, 512) -> tiled bf16 [tile][t][lk][128][8] ----------------
template<bool SPLIT>
__global__ __launch_bounds__(256) void conv_tile(
    const float* __restrict__ Xsrc,
    unsigned short* __restrict__ Thi, unsigned short* __restrict__ Tlo)
{
  const int bx = blockIdx.x;
  const int t  = blockIdx.y;
  const int tid = threadIdx.x;
  const int r = tid >> 1;
  const int h = tid & 1;
  const float* src = Xsrc + ((size_t)(bx*128 + r))*512 + t*32 + h*16;
  float xa[16];
#pragma unroll
  for (int q = 0; q < 4; ++q) {
    float4 v = *reinterpret_cast<const float4*>(src + 4*q);
    xa[4*q+0]=v.x; xa[4*q+1]=v.y; xa[4*q+2]=v.z; xa[4*q+3]=v.w;
  }
  size_t base = ((size_t)(bx*16 + t))*4096;
#pragma unroll
  for (int c = 0; c < 2; ++c) {
    int lk = h*2 + c;
    bf16x8 vh, vl;
#pragma unroll
    for (int e = 0; e < 8; ++e) {
      unsigned short hh = bf16_rne(xa[c*8+e]);
      vh[e] = (short)hh;
      if (SPLIT) vl[e] = (short)bf16_rne(xa[c*8+e] - bf16_f(hh));
    }
    *reinterpret_cast<bf16x8*>(Thi + base + ((size_t)lk*128 + r)*8) = vh;
    if (SPLIT)
      *reinterpret_cast<bf16x8*>(Tlo + base + ((size_t)lk*128 + r)*8) = vl;
  }
}

// ---------------- gemm_qk: single-conversion, split-bf16, fp32 transposed output ----------------
// grid (1024, 2): x=lt (64-l tile), y=sel (Q/K). 512 threads = 8 waves,
// wave w: n in [w*64, +64), l full 64. acc = 64 AGPR; X converted once/elem.
__global__ __launch_bounds__(512, 4) void gemm_qk(
    const float* __restrict__ Xq, const float* __restrict__ Xk,
    const unsigned short* __restrict__ Wqhi, const unsigned short* __restrict__ Wqlo,
    const unsigned short* __restrict__ Wkhi, const unsigned short* __restrict__ Wklo,
    const float* __restrict__ bq, const float* __restrict__ bk,
    float* __restrict__ Yq, float* __restrict__ Yk)
{
  __shared__ unsigned short Xh[2][2048], Xl[2][2048];
  const int sel = blockIdx.y;
  const float* X = sel ? Xk : Xq;
  const unsigned short* Whi = sel ? Wkhi : Wqhi;
  const unsigned short* Wlo = sel ? Wklo : Wqlo;
  const float* bias = sel ? bk : bq;
  float* Y = sel ? Yk : Yq;

  const int tid  = threadIdx.x;
  const int lt   = blockIdx.x;
  const int wave = tid >> 6;          // 0..7
  const int lane = tid & 63;
  const int lr   = lane & 15;
  const int lk   = lane >> 4;
  const int n0   = wave*64;
  // conversion: 2048 elems (64 l x 32 k) per t, 512 threads -> 4 elems each
  const int cr   = tid >> 3;          // l 0..63
  const int ch   = tid & 7;           // k-quad 0..7
  const int lkw  = ch >> 1;           // k-octet
  const int chh  = ch & 1;            // half of octet
  const int t0   = lt & 15;

  f32x4 acc[4][4];
#pragma unroll
  for (int i = 0; i < 4; ++i)
#pragma unroll
    for (int j = 0; j < 4; ++j) acc[i][j] = (f32x4){0.f,0.f,0.f,0.f};

  const float* Xb = X + ((size_t)(lt*64 + cr))*512 + ch*4;
  const int cu = ((lkw*64 + cr) ^ (lkw*2))*8 + chh*4;   // short offset in plane

  for (int it = 0; it < 16; ++it) {
    const int t = (t0 + it) & 15;
    const int p = it & 1;
    {
      float4 v0 = *reinterpret_cast<const float4*>(Xb + t*32);
      float xa[4] = {v0.x, v0.y, v0.z, v0.w};
      unsigned short h[4], lo[4];
#pragma unroll
      for (int e = 0; e < 4; ++e) {
        h[e]  = bf16_rne(xa[e]);
        lo[e] = bf16_rne(xa[e] - bf16_f(h[e]));
      }
      uint2 hi2 = make_uint2((unsigned)h[0]  | ((unsigned)h[1]  << 16),
                             (unsigned)h[2]  | ((unsigned)h[3]  << 16));
      uint2 lo2 = make_uint2((unsigned)lo[0] | ((unsigned)lo[1] << 16),
                             (unsigned)lo[2] | ((unsigned)lo[3] << 16));
      *reinterpret_cast<uint2*>(&Xh[p][cu]) = hi2;
      *reinterpret_cast<uint2*>(&Xl[p][cu]) = lo2;
    }
    bf16x8 ah[4], al[4];
#pragma unroll
    for (int i = 0; i < 4; ++i) {
      int n = n0 + i*16 + lr;
      size_t o = ((size_t)((n>>7)*16 + t))*4096 + ((size_t)lk*128 + (n&127))*8;
      ah[i] = *reinterpret_cast<const bf16x8*>(Whi + o);
      al[i] = *reinterpret_cast<const bf16x8*>(Wlo + o);
    }
    __syncthreads();

    __builtin_amdgcn_s_setprio(1);
#pragma unroll
    for (int j = 0; j < 4; ++j) {
      int u = (lk*64 + (j*16 + lr)) ^ (lk*2);
      bf16x8 bh = *reinterpret_cast<const bf16x8*>(&Xh[p][u*8]);
      bf16x8 bl = *reinterpret_cast<const bf16x8*>(&Xl[p][u*8]);
#pragma unroll
      for (int i = 0; i < 4; ++i)
        acc[i][j] = __builtin_amdgcn_mfma_f32_16x16x32_bf16(ah[i], bh, acc[i][j], 0, 0, 0);
#pragma unroll
      for (int i = 0; i < 4; ++i)
        acc[i][j] = __builtin_amdgcn_mfma_f32_16x16x32_bf16(ah[i], bl, acc[i][j], 0, 0, 0);
#pragma unroll
      for (int i = 0; i < 4; ++i)
        acc[i][j] = __builtin_amdgcn_mfma_f32_16x16x32_bf16(al[i], bh, acc[i][j], 0, 0, 0);
    }
    __builtin_amdgcn_s_setprio(0);
  }

  const int bb = lt >> 6;
  const int lbase = (lt & 63)*64;
#pragma unroll
  for (int i = 0; i < 4; ++i) {
    int n = n0 + i*16 + lk*4;
#pragma unroll
    for (int j = 0; j < 4; ++j) {
      int l = lbase + j*16 + lr;
#pragma unroll
      for (int r = 0; r < 4; ++r) {
        Y[((size_t)(bb*512 + n + r))*4096 + l] = acc[i][j][r] + bias[n + r];
      }
    }
  }
}

// ---------------- gemm_ov: fused values conversion, pure bf16, bf16 output ----------------
__global__ __launch_bounds__(512) void gemm_ov(
    const float* __restrict__ V, const unsigned short* __restrict__ Wct,
    const float* __restrict__ bias, unsigned short* __restrict__ Y16)
{
  __shared__ unsigned short Vs[2][256*8];
  const int tid  = threadIdx.x;
  const int bx   = blockIdx.x;
  const int wave = tid >> 6;
  const int lane = tid & 63;
  const int lr   = lane & 15;
  const int lk   = lane >> 4;
  const int n0   = wave*64;
  const int cr   = tid >> 3;
  const int ch   = tid & 7;
  const int clk  = ch >> 1;
  const int chh  = ch & 1;
  const int coff = (((clk*64 + cr) ^ clk)*8 + chh*4);
  const int t0   = bx & 15;

  f32x4 acc[4][4];
#pragma unroll
  for (int i = 0; i < 4; ++i)
#pragma unroll
    for (int j = 0; j < 4; ++j) acc[i][j] = (f32x4){0.f,0.f,0.f,0.f};

  const float* Vb = V + (size_t)bx*64*512 + (size_t)cr*512 + ch*4;
  float4 xv = *reinterpret_cast<const float4*>(Vb + t0*32);

  for (int it = 0; it < 16; ++it) {
    const int t = (t0 + it) & 15;
    const int p = it & 1;
    uint2 hi2 = make_uint2(
        (unsigned)bf16_rne(xv.x) | ((unsigned)bf16_rne(xv.y) << 16),
        (unsigned)bf16_rne(xv.z) | ((unsigned)bf16_rne(xv.w) << 16));
    *reinterpret_cast<uint2*>(&Vs[p][coff]) = hi2;
    float4 xnext;
    if (it < 15) {
      int tn = (t0 + it + 1) & 15;
      xnext = *reinterpret_cast<const float4*>(Vb + tn*32);
    }
    __syncthreads();

    bf16x8 av[4];
#pragma unroll
    for (int i = 0; i < 4; ++i) {
      int u = ((lk*64 + i*16 + lr) ^ lk)*8;
      av[i] = *reinterpret_cast<const bf16x8*>(&Vs[p][u]);
    }
#pragma unroll
    for (int j = 0; j < 4; ++j) {
      int n = n0 + j*16 + lr;
      size_t o = ((size_t)((n>>7)*16 + t))*4096 + ((size_t)lk*128 + (n&127))*8;
      bf16x8 bw = *reinterpret_cast<const bf16x8*>(Wct + o);
#pragma unroll
      for (int i = 0; i < 4; ++i)
        acc[i][j] = __builtin_amdgcn_mfma_f32_16x16x32_bf16(av[i], bw, acc[i][j], 0, 0, 0);
    }
    if (it < 15) xv = xnext;
  }

#pragma unroll
  for (int i = 0; i < 4; ++i) {
#pragma unroll
    for (int j = 0; j < 4; ++j) {
      int n = n0 + j*16 + lr;
      float bs = bias[n];
#pragma unroll
      for (int r = 0; r < 4; ++r) {
        int m = bx*64 + i*16 + lk*4 + r;
        Y16[(size_t)m*512 + n] = bf16_rne(acc[i][j][r] + bs);
      }
    }
  }
}

// ---------------- combine: Wc = Wo@Wv, bc = Wo@bv + bo ----------------
__global__ __launch_bounds__(256) void combine_kernel(
    const float* __restrict__ Wo, const float* __restrict__ Wv,
    const float* __restrict__ bv, const float* __restrict__ bo,
    float* __restrict__ Wc, float* __restrict__ bc)
{
  int n = blockIdx.x;
  int tid = threadIdx.x;
  float a0 = 0.f, a1 = 0.f;
  for (int j = 0; j < 512; ++j) {
    float wo = Wo[(size_t)n*512 + j];
    a0 += wo * Wv[(size_t)j*512 + tid];
    a1 += wo * Wv[(size_t)j*512 + tid + 256];
  }
  Wc[(size_t)n*512 + tid]       = a0;
  Wc[(size_t)n*512 + tid + 256] = a1;

  float p = 0.f;
  for (int j = tid; j < 512; j += 256) p += Wo[(size_t)n*512 + j] * bv[j];
  __shared__ float red[256];
  red[tid] = p; __syncthreads();
  for (int off = 128; off > 0; off >>= 1) {
    if (tid < off) red[tid] += red[tid + off];
    __syncthreads();
  }
  if (tid == 0) bc[n] = red[0] + bo[n];
}

// ---------------- twiddles ----------------
__global__ void init_tw_kernel(float2* __restrict__ tw) {
  int k = blockIdx.x * 256 + threadIdx.x;
  if (k < 4096) {
    double ang = -2.0 * M_PI * (double)k / 4096.0;
    tw[k] = make_float2((float)cos(ang), (float)sin(ang));
  }
}

// ---------------- packed FFT -> half-spectrum partials (Hermitian) ----------------
template<int CHB>
__global__ __launch_bounds__(256) void fft_corr_kernel(
    const float* __restrict__ Qt, const float* __restrict__ Kt,
    const float2* __restrict__ tw, float2* __restrict__ Spart)
{
  __shared__ float2 buf[4096];
  const int NG = 512 / CHB;
  const int b = blockIdx.x / NG;
  const int g = blockIdx.x % NG;
  const int tid = threadIdx.x;

  float2 acc[8];
#pragma unroll
  for (int m = 0; m < 8; ++m) acc[m] = make_float2(0.f, 0.f);

  for (int cc = 0; cc < CHB; ++cc) {
    const float* Qr = Qt + ((size_t)b*512 + g*CHB + cc) * 4096;
    const float* Kr = Kt + ((size_t)b*512 + g*CHB + cc) * 4096;
#pragma unroll
    for (int j = 0; j < 4; ++j) {
      int l0 = 4*(tid + 256*j);
      float4 q4 = *reinterpret_cast<const float4*>(Qr + l0);
      float4 k4 = *reinterpret_cast<const float4*>(Kr + l0);
      buf[l0+0] = make_float2(q4.x, k4.x);
      buf[l0+1] = make_float2(q4.y, k4.y);
      buf[l0+2] = make_float2(q4.z, k4.z);
      buf[l0+3] = make_float2(q4.w, k4.w);
    }
    __syncthreads();

    fft4096_stages(buf, tid, tw);

#pragma unroll
    for (int m = 0; m < 8; ++m) {
      int f = tid + 256*m;
      float2 zf = buf[f];
      float2 zm = buf[(4096 - f) & 4095];
      float2 qf = make_float2(0.5f*(zf.x + zm.x), 0.5f*(zf.y - zm.y));
      float2 df = make_float2(0.5f*(zf.x - zm.x), 0.5f*(zf.y + zm.y));
      float2 kf = make_float2(df.y, -df.x);
      acc[m].x += qf.x*kf.x + qf.y*kf.y;
      acc[m].y += qf.y*kf.x - qf.x*kf.y;   // == 0 at f==0
    }
    if (tid == 0) {
      float2 z2 = buf[2048];
      acc[0].y += z2.x * z2.y;
    }
    __syncthreads();
  }
  float2* Sp = Spart + ((size_t)(b*NG + g)) * 2048;
#pragma unroll
  for (int m = 0; m < 8; ++m) Sp[tid + 256*m] = acc[m];
}

// ---------------- reduce half-spectrum over groups, store conj (except bin0 pack) ----------------
__global__ __launch_bounds__(256) void reduce_spart_kernel(
    const float2* __restrict__ Spart, float2* __restrict__ S, int ng)
{
  const int b  = blockIdx.x >> 3;
  const int f  = ((blockIdx.x & 7) << 8) | threadIdx.x;
  float sx = 0.f, sy = 0.f;
  const float2* base = Spart + (size_t)b * ng * 2048 + f;
  for (int g = 0; g < ng; ++g) {
    float2 v = base[(size_t)g * 2048];
    sx += v.x; sy += v.y;
  }
  S[(size_t)b*2048 + f] = (f == 0) ? make_float2(sx, sy) : make_float2(sx, -sy);
}

// ---------------- inverse FFT per batch (Hermitian reconstruct) -> corr_mean ----------------
__global__ __launch_bounds__(256) void ifft_kernel(
    const float2* __restrict__ S, const float2* __restrict__ tw,
    float* __restrict__ corr)
{
  __shared__ float2 buf[4096];
  const int b = blockIdx.x;
  const int tid = threadIdx.x;
#pragma unroll
  for (int m = 0; m < 8; ++m) {
    int f = tid + 256*m;
    float2 s = S[(size_t)b*2048 + f];
    if (f == 0) {
      buf[0]    = make_float2(s.x, 0.f);
      buf[2048] = make_float2(s.y, 0.f);
    } else {
      buf[f]        = s;
      buf[4096 - f] = make_float2(s.x, -s.y);
    }
  }
  __syncthreads();
  fft4096_stages(buf, tid, tw);
  const float scale = 1.0f / (512.0f * 4096.0f);
#pragma unroll
  for (int m = 0; m < 16; ++m) {
    int t = tid + 256*m;
    corr[(size_t)b*4096 + t] = buf[t].x * scale;
  }
}

// ---------------- top-18 per batch + ambiguity flag ----------------
__global__ __launch_bounds__(256) void topk_kernel(
    const float* __restrict__ corr, float* __restrict__ cand_val,
    int* __restrict__ cand_idx, int* __restrict__ flags)
{
  __shared__ float vals[4096];
  __shared__ float rv[256];
  __shared__ int   ri[256];
  const int b = blockIdx.x;
  const int tid = threadIdx.x;
#pragma unroll
  for (int r = 0; r < 16; ++r) vals[tid + 256*r] = corr[(size_t)b*4096 + tid + 256*r];
  __syncthreads();

  for (int it = 0; it < NCAND; ++it) {
    float best = -1e30f; int bi = -1;
#pragma unroll
    for (int r = 0; r < 16; ++r) {
      int i = tid + 256*r;
      float v = vals[i];
      if (v > best) { best = v; bi = i; }
    }
    rv[tid] = best; ri[tid] = bi;
    __syncthreads();
    for (int off = 128; off > 0; off >>= 1) {
      if (tid < off) {
        float v2 = rv[tid + off]; int i2 = ri[tid + off];
        if (v2 > rv[tid] || (v2 == rv[tid] && i2 < ri[tid])) { rv[tid] = v2; ri[tid] = i2; }
      }
      __syncthreads();
    }
    if (tid == 0) {
      cand_val[b*NCAND + it] = rv[0];
      cand_idx[b*NCAND + it] = ri[0];
      vals[ri[0]] = -1e30f;
    }
    __syncthreads();
  }
  if (tid == 0)
    flags[b] = (cand_val[b*NCAND + 15] - cand_val[b*NCAND + 16] < 2e-6f) ? 1 : 0;
}

// ---------------- exact refinement: read-once, all 18 taus ----------------
__global__ __launch_bounds__(256) void refine_kernel(
    const float* __restrict__ Qt, const float* __restrict__ Kt,
    const int* __restrict__ cand_idx, const int* __restrict__ flags,
    float* __restrict__ refpart)
{
  const int b = blockIdx.x >> 5;
  const int chunk = blockIdx.x & 31;
  if (!flags[b]) return;
  __shared__ float Qs[4096];
  __shared__ float red[4*NCAND];
  const int tid = threadIdx.x;
  int taus[NCAND];
#pragma unroll
  for (int i = 0; i < NCAND; ++i) taus[i] = cand_idx[b*NCAND + i];
  float acc[NCAND];
#pragma unroll
  for (int i = 0; i < NCAND; ++i) acc[i] = 0.f;

  for (int cc = 0; cc < 16; ++cc) {
    int c = chunk*16 + cc;
    const float* Qc = Qt + ((size_t)b*512 + c)*4096;
    const float* Kc = Kt + ((size_t)b*512 + c)*4096;
    __syncthreads();
#pragma unroll
    for (int rr = 0; rr < 4; ++rr) {
      int l4 = (tid + 256*rr)*4;
      *reinterpret_cast<float4*>(&Qs[l4]) = *reinterpret_cast<const float4*>(Qc + l4);
    }
    __syncthreads();
#pragma unroll 2
    for (int j = 0; j < 16; ++j) {
      int l = tid + 256*j;
      float kv = Kc[l];
#pragma unroll
      for (int i = 0; i < NCAND; ++i)
        acc[i] += Qs[(l + taus[i]) & 4095] * kv;
    }
  }
#pragma unroll
  for (int i = 0; i < NCAND; ++i) {
    float v = acc[i];
    for (int off = 32; off > 0; off >>= 1) v += __shfl_down(v, off);
    if ((tid & 63) == 0) red[(tid >> 6)*NCAND + i] = v;
  }
  __syncthreads();
  if (tid < NCAND) {
    float s = red[tid] + red[NCAND + tid] + red[2*NCAND + tid] + red[3*NCAND + tid];
    refpart[(size_t)(b*32 + chunk)*NCAND + tid] = s;
  }
}

// ---------------- select top-16 of 18 (with inline refinement sum), softmax ----------------
__global__ void probs_kernel(const float* __restrict__ cand_val,
                             const float* __restrict__ refpart,
                             const int* __restrict__ flags,
                             const int* __restrict__ cand_idx,
                             float* __restrict__ probs, int* __restrict__ delays)
{
  int b = blockIdx.x;
  __shared__ float vloc[NCAND];
  int t = threadIdx.x;
  if (t < NCAND) {
    float v = cand_val[b*NCAND + t];
    if (flags[b]) {
      double s = 0.0;
      for (int g = 0; g < 32; ++g) s += (double)refpart[(size_t)(b*32 + g)*NCAND + t];
      v = (float)(s / 512.0);
    }
    vloc[t] = v;
  }
  __syncthreads();
  if (t != 0) return;
  float v[NCAND]; int ix[NCAND]; bool used[NCAND];
  for (int i = 0; i < NCAND; ++i) {
    v[i] = vloc[i]; ix[i] = cand_idx[b*NCAND + i]; used[i] = false;
  }
  float sel_v[KTOP]; int sel_i[KTOP];
  for (int k = 0; k < KTOP; ++k) {
    int best = -1;
    for (int i = 0; i < NCAND; ++i) {
      if (used[i]) continue;
      if (best < 0 || v[i] > v[best] || (v[i] == v[best] && ix[i] < ix[best])) best = i;
    }
    used[best] = true; sel_v[k] = v[best]; sel_i[k] = ix[best];
  }
  float mx = sel_v[0];
  for (int k = 1; k < KTOP; ++k) mx = fmaxf(mx, sel_v[k]);
  float e[KTOP]; float se = 0.f;
  for (int k = 0; k < KTOP; ++k) { e[k] = __expf(sel_v[k] - mx); se += e[k]; }
  for (int k = 0; k < KTOP; ++k) {
    probs[b*KTOP + k]  = e[k] / se;
    delays[b*KTOP + k] = sel_i[k];
  }
}

// ---------------- shift-aggregate: bf16 OV gather, XCD-pinned batches ----------------
__global__ __launch_bounds__(256) void agg_kernel(
    const unsigned short* __restrict__ OV, const float* __restrict__ probs,
    const int* __restrict__ delays, float* __restrict__ out)
{
  int half = blockIdx.x >> 13;
  int bid2 = blockIdx.x & 8191;
  int b  = half*8 + (bid2 & 7);
  int l  = (bid2 >> 3) * 4 + (threadIdx.x >> 6);
  int c8 = (threadIdx.x & 63) << 3;
  float p[KTOP]; int d[KTOP];
#pragma unroll
  for (int i = 0; i < KTOP; ++i) { p[i] = probs[b*KTOP + i]; d[i] = delays[b*KTOP + i]; }
  float acc[8];
#pragma unroll
  for (int j = 0; j < 8; ++j) acc[j] = 0.f;
#pragma unroll
  for (int i = 0; i < KTOP; ++i) {
    int ls = (l + d[i]) & 4095;
    uint4 v = *reinterpret_cast<const uint4*>(OV + ((size_t)((b << 12) | ls))*512 + c8);
    unsigned int uu[4] = {v.x, v.y, v.z, v.w};
    float pi = p[i];
#pragma unroll
    for (int t = 0; t < 4; ++t) {
      acc[2*t]   += pi * __uint_as_float(uu[t] << 16);
      acc[2*t+1] += pi * __uint_as_float(uu[t] & 0xFFFF0000u);
    }
  }
  float* dst = out + ((size_t)((b << 12) | l))*512 + c8;
  *reinterpret_cast<float4*>(dst)     = make_float4(acc[0], acc[1], acc[2], acc[3]);
  *reinterpret_cast<float4*>(dst + 4) = make_float4(acc[4], acc[5], acc[6], acc[7]);
}

// ---------------- launch ----------------
extern "C" void kernel_launch(void* const* d_in, const int* in_sizes, int n_in,
                              void* d_out, int out_size, void* d_ws, size_t ws_size,
                              hipStream_t stream)
{
  const float* queries = (const float*)d_in[0];
  const float* keys    = (const float*)d_in[1];
  const float* values  = (const float*)d_in[2];
  const float* Wq = (const float*)d_in[3];
  const float* bq = (const float*)d_in[4];
  const float* Wk = (const float*)d_in[5];
  const float* bk = (const float*)d_in[6];
  const float* Wv = (const float*)d_in[7];
  const float* bv = (const float*)d_in[8];
  const float* Wo = (const float*)d_in[9];
  const float* bo = (const float*)d_in[10];

  const size_t WT = (size_t)E_*E_*2;
  const size_t fixed = (size_t)B_*E_*L_*4
                     + (size_t)B_*2048*8
                     + (size_t)B_*L_*4
                     + (size_t)E_*E_*4 + E_*4
                     + (size_t)4096*8
                     + (size_t)B_*NCAND*8 + B_*4
                     + (size_t)B_*KTOP*8
                     + (size_t)B_*32*NCAND*4
                     + 5*WT;
  int NG;
  if (ws_size >= fixed + (size_t)B_*128*2048*8)      NG = 128;
  else if (ws_size >= fixed + (size_t)B_*64*2048*8)  NG = 64;
  else                                               NG = 32;

  char* ws = (char*)d_ws;
  size_t off = 0;
  float* Qt   = (float*)(ws + off);    off += (size_t)B_*E_*L_*4;
  float2* Spart = (float2*)(ws + off); off += (size_t)B_*NG*2048*8;
  float2* S   = (float2*)(ws + off);   off += (size_t)B_*2048*8;
  float* corr = (float*)(ws + off);    off += (size_t)B_*L_*4;
  float* Wc   = (float*)(ws + off);    off += (size_t)E_*E_*4;
  float* bc   = (float*)(ws + off);    off += (size_t)E_*4;
  float2* tw  = (float2*)(ws + off);   off += (size_t)4096*8;
  float* cand_val = (float*)(ws + off); off += (size_t)B_*NCAND*4;
  int*   cand_idx = (int*)(ws + off);   off += (size_t)B_*NCAND*4;
  int*   flags    = (int*)(ws + off);   off += (size_t)B_*4;
  float* probs    = (float*)(ws + off); off += (size_t)B_*KTOP*4;
  int*   delays   = (int*)(ws + off);   off += (size_t)B_*KTOP*4;
  float* refpart  = (float*)(ws + off); off += (size_t)B_*32*NCAND*4;
  unsigned short* Wqhi = (unsigned short*)(ws + off); off += WT;
  unsigned short* Wqlo = (unsigned short*)(ws + off); off += WT;
  unsigned short* Wkhi = (unsigned short*)(ws + off); off += WT;
  unsigned short* Wklo = (unsigned short*)(ws + off); off += WT;
  unsigned short* Wcthi = (unsigned short*)(ws + off); off += WT;

  float* Kt = (float*)d_out;                  // d_out is K scratch until agg
  unsigned short* OV = (unsigned short*)Qt;   // bf16 OV overlays Qt after refine

  init_tw_kernel<<<16, 256, 0, stream>>>(tw);
  conv_tile<true><<<dim3(4,16), 256, 0, stream>>>(Wq, Wqhi, Wqlo);
  conv_tile<true><<<dim3(4,16), 256, 0, stream>>>(Wk, Wkhi, Wklo);
  combine_kernel<<<E_, 256, 0, stream>>>(Wo, Wv, bv, bo, Wc, bc);
  conv_tile<false><<<dim3(4,16), 256, 0, stream>>>(Wc, Wcthi, Wcthi);

  gemm_qk<<<dim3(1024, 2), 512, 0, stream>>>(queries, keys, Wqhi, Wqlo, Wkhi, Wklo,
                                             bq, bk, Qt, Kt);

  if (NG == 128)
    fft_corr_kernel<4><<<B_*128, 256, 0, stream>>>(Qt, Kt, tw, Spart);
  else if (NG == 64)
    fft_corr_kernel<8><<<B_*64, 256, 0, stream>>>(Qt, Kt, tw, Spart);
  else
    fft_corr_kernel<16><<<B_*32, 256, 0, stream>>>(Qt, Kt, tw, Spart);
  reduce_spart_kernel<<<B_*8, 256, 0, stream>>>(Spart, S, NG);
  ifft_kernel<<<B_, 256, 0, stream>>>(S, tw, corr);
  topk_kernel<<<B_, 256, 0, stream>>>(corr, cand_val, cand_idx, flags);
  refine_kernel<<<B_*32, 256, 0, stream>>>(Qt, Kt, cand_idx, flags, refpart);
  probs_kernel<<<B_, 64, 0, stream>>>(cand_val, refpart, flags, cand_idx, probs, delays);

  gemm_ov<<<1024, 512, 0, stream>>>(values, Wcthi, bc, OV);
  agg_kernel<<<16384, 256, 0, stream>>>(OV, probs, delays, (float*)d_out);
}